// Round 4
// baseline (496.416 us; speedup 1.0000x reference)
//
#include <hip/hip_runtime.h>
#include <math.h>

// Problem constants
#define NN   2048
#define EE   8192
#define CNF  256
#define MN   16384
#define ME   65536
#define KK   1024

// Output layout (float element offsets)
#define OUT_XN   ((size_t)0)
#define OUT_L0   ((size_t)262144)
#define OUT_XE   ((size_t)1310720)
#define OUT_L1   ((size_t)3407872)
#define OUT_PM   ((size_t)70516736)
#define OUT_XN0  ((size_t)78905344)
#define OUT_XE0  ((size_t)79167488)

// Workspace layout (element offsets)
#define WS_T1N    0
#define WS_SLINN  2048
#define WS_T1E    4096
#define WS_SLINE  12288
#define WS_SCN    20480
#define WS_SCE    22528
#define WS_JOINT  30720   // dead gap 30720..32767 (2048 floats) — no ws growth
#define WS_AGGN   32768
#define WS_AGGE   34816
#define WS_LAM    43008
#define WS_IDXK   43520
#define WS_RANK   44544
#define WS_OFFS   47616
#define WS_ADJE   66176   // int[16384]
#define WS_KEEPE  82560   // int[8192]

#define DCAP  8
#define PWR_T 64          // 96->64: Rayleigh error (lam_i/lam_1)^128-weighted, ~1e-4 rel
#define RBAD  0xFFFFu

// native vector for nontemporal builtin (HIP float4 is a class -> rejected)
typedef float vf4 __attribute__((ext_vector_type(4)));

// =====================================================================
// Kernel A: row dots (wave per row) + zero the ws accumulators.
// =====================================================================
__global__ void k_prep(const float* __restrict__ xn, const float* __restrict__ xe,
                       const float* __restrict__ Wn0, const float* __restrict__ Wn1,
                       const float* __restrict__ We0, const float* __restrict__ We1,
                       float* __restrict__ wsf) {
    if (blockIdx.x == 0) {   // zero accumulators (AGGN, AGGE) + joint
        for (int i = threadIdx.x; i < 2048; i += 256) wsf[WS_AGGN + i] = 0.f;
        for (int i = threadIdx.x; i < 8192; i += 256) wsf[WS_AGGE + i] = 0.f;
        for (int i = threadIdx.x; i < 2048; i += 256) wsf[WS_JOINT + i] = 0.f;
    }
    int gw = (blockIdx.x * blockDim.x + threadIdx.x) >> 6;
    int lane = threadIdx.x & 63;
    int wstr = (gridDim.x * blockDim.x) >> 6;
    for (int row = gw; row < NN + EE; row += wstr) {
        const float *x, *W0, *W1; float *t1, *sl; int r;
        if (row < NN) { r = row;      x = xn + (size_t)r * CNF; W0 = Wn0; W1 = Wn1; t1 = wsf + WS_T1N; sl = wsf + WS_SLINN; }
        else          { r = row - NN; x = xe + (size_t)r * CNF; W0 = We0; W1 = We1; t1 = wsf + WS_T1E; sl = wsf + WS_SLINE; }
        float4 xv = ((const float4*)x)[lane];
        float4 w0 = ((const float4*)W0)[lane];
        float4 w1 = ((const float4*)W1)[lane];
        float d0 = xv.x*w0.x + xv.y*w0.y + xv.z*w0.z + xv.w*w0.w;
        float d1 = xv.x*w1.x + xv.y*w1.y + xv.z*w1.z + xv.w*w1.w;
        #pragma unroll
        for (int o = 32; o > 0; o >>= 1) { d0 += __shfl_down(d0, o, 64); d1 += __shfl_down(d1, o, 64); }
        if (lane == 0) { t1[r] = d1; sl[r] = d0 + d1; }
    }
}

// =====================================================================
// Kernel B: conv-edge scatter, grid-wide (single-CU version cost ~200us).
// =====================================================================
__global__ void k_agg(const int* __restrict__ ein, const float* __restrict__ ewn,
                      const int* __restrict__ eie, const float* __restrict__ ewe,
                      float* __restrict__ wsf) {
    int i = blockIdx.x * blockDim.x + threadIdx.x;
    if (i < MN) {
        int s = ein[i], d = ein[MN + i];
        atomicAdd(wsf + WS_AGGN + d, ewn[i] * wsf[WS_T1N + s]);
    }
    if (i < ME) {
        int s = eie[i], d = eie[ME + i];
        atomicAdd(wsf + WS_AGGE + d, ewe[i] * wsf[WS_T1E + s]);
    }
}

// =====================================================================
// Kernel B2: grid-wide sigmoid scores + joint node score (order-indep
// pure atomicAdd into pre-zeroed joint).
// =====================================================================
__global__ void k_score(const int* __restrict__ ei,
                        const float* __restrict__ bn, const float* __restrict__ be,
                        float* __restrict__ wsf) {
    int i = blockIdx.x * blockDim.x + threadIdx.x;
    if (i < NN) {
        float z = wsf[WS_SLINN + i] - wsf[WS_AGGN + i] + bn[0];
        float s = 1.0f / (1.0f + expf(-z));
        wsf[WS_SCN + i] = s;
        atomicAdd(wsf + WS_JOINT + i, s);
    }
    if (i < EE) {
        float z = wsf[WS_SLINE + i] - wsf[WS_AGGE + i] + be[0];
        float s = 1.0f / (1.0f + expf(-z));
        wsf[WS_SCE + i] = s;
        float v = 0.125f * s;
        atomicAdd(wsf + WS_JOINT + ei[i], v);        // src (+1 in |B|)
        atomicAdd(wsf + WS_JOINT + ei[EE + i], v);   // dst (+1 in |B|; s==d -> 2x, matches ref)
    }
}

// --------------------------------------------------- block reduce (4 waves)
__device__ __forceinline__ float block_reduce_sum_256(float val, float* red) {
    #pragma unroll
    for (int o = 32; o > 0; o >>= 1) val += __shfl_down(val, o, 64);
    int lane = threadIdx.x & 63, wid = threadIdx.x >> 6;   // wid 0..3
    if (lane == 0) red[wid] = val;
    __syncthreads();
    float r = 0.0f;
    if (threadIdx.x < 64) {
        r = (threadIdx.x < 4) ? red[threadIdx.x] : 0.0f;
        #pragma unroll
        for (int o = 2; o > 0; o >>= 1) r += __shfl_down(r, o, 64);
        if (threadIdx.x == 0) red[0] = r;
    }
    __syncthreads();
    float out = red[0];
    __syncthreads();
    return out;
}

// --------------------------------------------------- block inclusive scan
// 1024 threads (16 waves): per-wave shfl scan + 16-partial combine. 2 barriers.
// Caller must barrier before t16 is reused.
__device__ __forceinline__ int block_incl_scan_1024(int v, int* t16) {
    int lane = threadIdx.x & 63, wid = threadIdx.x >> 6;
    int x = v;
    #pragma unroll
    for (int o = 1; o < 64; o <<= 1) {
        int t = __shfl_up(x, o, 64);
        if (lane >= o) x += t;
    }
    if (lane == 63) t16[wid] = x;
    __syncthreads();
    if (threadIdx.x < 16) {
        int w = t16[threadIdx.x];
        #pragma unroll
        for (int o = 1; o < 16; o <<= 1) {
            int t = __shfl_up(w, o, 16);
            if ((int)threadIdx.x >= o) w += t;
        }
        t16[threadIdx.x] = w;
    }
    __syncthreads();
    int base = wid ? t16[wid - 1] : 0;
    return base + x;
}

// =====================================================================
// Kernel C: block 0 = serial chain P5..P9, fully LDS-resident;
// blocks 1..255 zero L0+L1+PM (306 MB, nontemporal) meanwhile.
// R1 lesson: SINGLE-WAVE power iteration REGRESSED 4x — needs wave
// parallelism + DCAP register preload.
// R2: radix-select top-K + shfl scans: -21us. R3: P3/P4 offload: -18us
// (confirms chain-bound, zero stays hidden).
// R4 (this): (a) P5 per-wave histograms — kills the ~2048-deep LDS
// atomic serialization when all keys share a top digit (scores cluster
// in [0.5,2) -> one hot bin on pass 5). (b) P9 on 4 waves (waves 4..15
// exit after P8; CDNA s_barrier ignores exited waves): 4 nodes/thread,
// fully unrolled (static reg indexing), self value in reg. Cheaper
// barriers x88, same TLP*ILP product.
// =====================================================================
__global__ __launch_bounds__(1024) void k_mid(
        const int* __restrict__ ei,
        float* __restrict__ out, float* __restrict__ wsf, int* __restrict__ wsi) {
    int tid = threadIdx.x;
    if (blockIdx.x != 0) {
        // ------------- zeroers: L1, PM, L0 (nontemporal: no reuse pre-k_final) -------------
        size_t w = (size_t)(blockIdx.x - 1) * 1024 + tid;
        size_t ws = (size_t)(gridDim.x - 1) * 1024;
        vf4 z = (vf4)(0.0f);
        vf4* l1 = (vf4*)(out + OUT_L1);
        for (size_t p = w; p < (size_t)EE * EE / 4; p += ws) __builtin_nontemporal_store(z, &l1[p]);
        vf4* pm = (vf4*)(out + OUT_PM);
        for (size_t p = w; p < (size_t)KK * EE / 4; p += ws) __builtin_nontemporal_store(z, &pm[p]);
        vf4* l0 = (vf4*)(out + OUT_L0);
        for (size_t p = w; p < (size_t)KK * KK / 4; p += ws) __builtin_nontemporal_store(z, &l0[p]);
        return;
    }
    // ---------------- block 0: serial chain, LDS-resident ----------------
    __shared__ unsigned long long s_u64[2048];       // 16 KB: per-wave bins / deg+scan+cur / power v
    __shared__ unsigned short s_rank[2048];          // 4 KB
    __shared__ unsigned short s_adjo[16384 + DCAP];  // 32 KB (+pad for reg-preload)
    __shared__ float s_red[16];
    __shared__ int s_t16[16];
    int* s_i = (int*)s_u64;                          // 4096 ints, phase-aliased

    // P5: top-K via exact radix select on 43-bit key (sortkey<<11)|(2047-i).
    // Thread owns the ADJACENT pair (2t, 2t+1) so kept flags stay in regs.
    // Per-wave 256-bin histograms (16x256 = all of s_i) kill hot-bin
    // serialization; boundary wave sums the 16 slices directly.
    unsigned long long k0, k1;
    {
        int i0 = 2 * tid, i1 = 2 * tid + 1;
        float f0 = wsf[WS_JOINT + i0], f1 = wsf[WS_JOINT + i1];
        unsigned u0 = __float_as_uint(f0), u1 = __float_as_uint(f1);
        unsigned sk0 = (u0 & 0x80000000u) ? ~u0 : (u0 | 0x80000000u);
        unsigned sk1 = (u1 & 0x80000000u) ? ~u1 : (u1 | 0x80000000u);
        k0 = (((unsigned long long)sk0) << 11) | (unsigned long long)(2047 - i0);
        k1 = (((unsigned long long)sk1) << 11) | (unsigned long long)(2047 - i1);
    }
    unsigned long long prefix = 0ULL;
    int rem = KK;
    int wb = (tid >> 6) << 8;                  // this wave's histogram base
    #pragma unroll
    for (int p = 5; p >= 0; --p) {
        __syncthreads();                       // protect s_i reuse across passes
        for (int i = tid; i < 4096; i += 1024) s_i[i] = 0;
        __syncthreads();
        int sh = p << 3;
        unsigned long long ph = prefix >> (sh + 8);
        if ((k0 >> (sh + 8)) == ph) atomicAdd(&s_i[wb | (int)((k0 >> sh) & 255)], 1);
        if ((k1 >> (sh + 8)) == ph) atomicAdd(&s_i[wb | (int)((k1 >> sh) & 255)], 1);
        __syncthreads();
        if (tid < 64) {                        // wave 0: sum 16 slices + boundary digit
            int b0 = 0, b1 = 0, b2 = 0, b3 = 0;
            #pragma unroll
            for (int w = 0; w < 16; ++w) {
                int base = (w << 8) | (tid << 2);
                b0 += s_i[base]; b1 += s_i[base + 1]; b2 += s_i[base + 2]; b3 += s_i[base + 3];
            }
            int sl = b0 + b1 + b2 + b3;
            int si = sl;
            #pragma unroll
            for (int o = 1; o < 64; o <<= 1) {
                int t = __shfl_down(si, o, 64);
                if (tid + o < 64) si += t;
            }
            int sup = si - sl;                 // count with digit-group > this lane
            int sg3 = sup;
            int sg2 = sg3 + b3;
            int sg1 = sg2 + b2;
            int sg0 = sg1 + b1;
            // wave-lockstep: all slice reads retire before these stores
            if (sg0 < rem && rem <= sg0 + b0) { s_i[256] = (tid << 2) | 0; s_i[257] = rem - sg0; }
            if (sg1 < rem && rem <= sg1 + b1) { s_i[256] = (tid << 2) | 1; s_i[257] = rem - sg1; }
            if (sg2 < rem && rem <= sg2 + b2) { s_i[256] = (tid << 2) | 2; s_i[257] = rem - sg2; }
            if (sg3 < rem && rem <= sg3 + b3) { s_i[256] = (tid << 2) | 3; s_i[257] = rem - sg3; }
        }
        __syncthreads();
        prefix |= ((unsigned long long)(unsigned)s_i[256]) << sh;
        rem = s_i[257];
    }
    // prefix == exact 1024th-largest key. kept <=> key >= prefix (all keys distinct).
    {
        int a0 = (k0 >= prefix) ? 1 : 0;
        int a1 = (k1 >= prefix) ? 1 : 0;
        int pr = a0 + a1;
        __syncthreads();                       // s_i[256..257] reads done before t16/s_i reuse
        int incl = block_incl_scan_1024(pr, s_t16);
        int excl = incl - pr;
        int i0 = 2 * tid, i1 = 2 * tid + 1;
        int r0 = excl, r1 = excl + a0;
        s_rank[i0] = a0 ? (unsigned short)r0 : (unsigned short)RBAD;
        s_rank[i1] = a1 ? (unsigned short)r1 : (unsigned short)RBAD;
        wsi[WS_RANK + i0] = a0 ? r0 : -1;      // for k_final
        wsi[WS_RANK + i1] = a1 ? r1 : -1;
        if (a0) wsi[WS_IDXK + r0] = i0;
        if (a1) wsi[WS_IDXK + r1] = i1;
    }
    __syncthreads();

    // P6: degrees (LDS s_i[0..1023]) + keep_e flags (seq global write)
    s_i[tid] = 0;
    __syncthreads();
    for (int e = tid; e < EE; e += 1024) {
        int s = ei[e], d = ei[EE + e];
        unsigned rs = s_rank[s], rd = s_rank[d];
        int kept = (rs != RBAD && rd != RBAD);
        wsi[WS_KEEPE + e] = kept;
        if (kept && s != d) {
            atomicAdd(&s_i[(int)rs], 1);
            atomicAdd(&s_i[(int)rd], 1);
        }
    }
    __syncthreads();

    // P7: CSR offsets via shfl block scan; cur in s_i[2048..3071]
    {
        int dg = s_i[tid];
        int incl = block_incl_scan_1024(dg, s_t16);
        int offs = incl - dg;
        s_i[2048 + tid] = offs;                // cur
        wsi[WS_OFFS + tid] = offs;             // for k_final + power
        if (tid == 1023) wsi[WS_OFFS + 1024] = incl;
    }
    __syncthreads();

    // P8: CSR fill: adjo -> LDS u16 (power), adje -> global (k_final only)
    for (int e = tid; e < EE; e += 1024) {
        int s = ei[e], d = ei[EE + e];
        unsigned rs = s_rank[s], rd = s_rank[d];
        if (rs != RBAD && rd != RBAD && s != d) {
            int p = atomicAdd(&s_i[2048 + (int)rs], 1);
            s_adjo[p] = (unsigned short)rd;
            wsi[WS_ADJE + p] = (e << 1);
            int q = atomicAdd(&s_i[2048 + (int)rd], 1);
            s_adjo[q] = (unsigned short)rs;
            wsi[WS_ADJE + q] = (e << 1) | 1;
        }
    }
    __syncthreads();

    // P9: power iteration — 4 WAVES (waves 4..15 exit; CDNA s_barrier
    // ignores exited waves). 4 nodes/thread (n = tid + 256k), fully
    // unrolled -> aj/vself/y stay in registers. Self value in reg; only
    // neighbors read LDS. offs read from GLOBAL (v aliases s_i).
    if (tid >= 256) return;
    {
        int o0[4], dd[4];
        #pragma unroll
        for (int k = 0; k < 4; ++k) {
            int n = tid + (k << 8);
            o0[k] = wsi[WS_OFFS + n];
            dd[k] = wsi[WS_OFFS + n + 1] - o0[k];
        }
        float* v0 = (float*)s_u64;
        float* v1 = v0 + 1024;
        float vself[4];
        #pragma unroll
        for (int k = 0; k < 4; ++k) {
            int n = tid + (k << 8);
            unsigned h = (unsigned)n * 2654435761u + 911u;
            h ^= h >> 15; h *= 2246822519u; h ^= h >> 13;
            float iv = (float)(h & 0xFFFFu) * (1.0f / 65536.0f) - 0.5f;
            v0[n] = iv; vself[k] = iv;
        }
        int aj[4][DCAP];
        #pragma unroll
        for (int k = 0; k < 4; ++k) {
            #pragma unroll
            for (int j = 0; j < DCAP; ++j) aj[k][j] = (j < dd[k]) ? (int)s_adjo[o0[k] + j] : 0;
        }
        __syncthreads();
        float* vc = v0; float* vn = v1;
        for (int iter = 0; iter < PWR_T; ++iter) {
            float y[4]; float n2loc = 0.0f;
            #pragma unroll
            for (int k = 0; k < 4; ++k) {
                float acc = 0.0f;
                #pragma unroll
                for (int j = 0; j < DCAP; ++j) acc += (j < dd[k]) ? vc[aj[k][j]] : 0.0f;
                for (int i = o0[k] + DCAP; i < o0[k] + dd[k]; ++i) acc += vc[(int)s_adjo[i]];
                y[k] = (float)dd[k] * vself[k] - acc;
                n2loc += y[k] * y[k];
            }
            if ((iter & 7) == 7) {
                float n2 = block_reduce_sum_256(n2loc, s_red);
                float sc = (n2 > 0.0f) ? rsqrtf(n2) : 0.0f;
                #pragma unroll
                for (int k = 0; k < 4; ++k) y[k] *= sc;
            }
            #pragma unroll
            for (int k = 0; k < 4; ++k) { int n = tid + (k << 8); vn[n] = y[k]; vself[k] = y[k]; }
            __syncthreads();
            float* tmp = vc; vc = vn; vn = tmp;
        }
        // final matvec + Rayleigh (iter 63 normalized: ||v|| = 1)
        float numloc = 0.0f;
        #pragma unroll
        for (int k = 0; k < 4; ++k) {
            float acc = 0.0f;
            #pragma unroll
            for (int j = 0; j < DCAP; ++j) acc += (j < dd[k]) ? vc[aj[k][j]] : 0.0f;
            for (int i = o0[k] + DCAP; i < o0[k] + dd[k]; ++i) acc += vc[(int)s_adjo[i]];
            float y = (float)dd[k] * vself[k] - acc;
            numloc += vself[k] * y;
        }
        float rq = block_reduce_sum_256(numloc, s_red);
        if (tid == 0) wsf[WS_LAM] = rq;
    }
}

// =====================================================================
// Kernel D: all output writes that depend on the chain (2/lam folded).
// =====================================================================
__global__ __launch_bounds__(1024) void k_final(
        const float* __restrict__ xn, const float* __restrict__ xe,
        const float* __restrict__ xn0, const float* __restrict__ xe0,
        const int* __restrict__ ei,
        float* __restrict__ out, const float* __restrict__ wsf,
        const int* __restrict__ wsi) {
    float sc = 2.0f / wsf[WS_LAM];
    int gt = blockIdx.x * 1024 + threadIdx.x;
    int gstr = gridDim.x * 1024;

    // (a) kept-node feature gathers (rows fully overwritten, no pre-zero)
    for (int i = gt; i < KK * 64; i += gstr) {
        int r = i >> 6, c = i & 63;
        int src = wsi[WS_IDXK + r];
        float s = wsf[WS_SCN + src];
        float4 v = ((const float4*)(xn + (size_t)src * CNF))[c];
        v.x *= s; v.y *= s; v.z *= s; v.w *= s;
        ((float4*)(out + OUT_XN))[(size_t)r * 64 + c] = v;
        ((float4*)(out + OUT_XN0))[(size_t)r * 64 + c] = ((const float4*)(xn0 + (size_t)src * CNF))[c];
    }
    // (b) edge feature rows, written densely (kept: scaled; dropped: x*0)
    for (int i = gt; i < EE * 64; i += gstr) {
        int e = i >> 6, c = i & 63;
        float m = wsi[WS_KEEPE + e] ? 1.0f : 0.0f;
        float s = m * wsf[WS_SCE + e];
        float4 v = ((const float4*)(xe + (size_t)e * CNF))[c];
        v.x *= s; v.y *= s; v.z *= s; v.w *= s;
        ((float4*)(out + OUT_XE))[(size_t)e * 64 + c] = v;
        float4 v0 = ((const float4*)(xe0 + (size_t)e * CNF))[c];
        v0.x *= m; v0.y *= m; v0.z *= m; v0.w *= m;
        ((float4*)(out + OUT_XE0))[(size_t)e * 64 + c] = v0;
    }
    // (c) par_masked + L0 scatter (pre-zeroed in k_mid)
    {
        float* pm = out + OUT_PM;
        float* L0 = out + OUT_L0;
        for (int e = gt; e < EE; e += gstr) {
            int s = ei[e], d = ei[EE + e];
            int rs = wsi[WS_RANK + s], rd = wsi[WS_RANK + d];
            if (rs < 0 || rd < 0 || s == d) continue;
            pm[(size_t)rs * EE + e] = -1.0f;
            pm[(size_t)rd * EE + e] =  1.0f;
            atomicAdd(&L0[(size_t)rs * KK + rs],  sc);
            atomicAdd(&L0[(size_t)rd * KK + rd],  sc);
            atomicAdd(&L0[(size_t)rs * KK + rd], -sc);
            atomicAdd(&L0[(size_t)rd * KK + rs], -sc);
        }
    }
    // (d) L1 scatter: wave per node-row, lanes over inner pairs
    {
        float* L1 = out + OUT_L1;
        int gwv = gt >> 6, lane = gt & 63, wstr = gstr >> 6;
        for (int r = gwv; r < KK; r += wstr) {
            int o0 = wsi[WS_OFFS + r], o1 = wsi[WS_OFFS + r + 1];
            for (int i = o0; i < o1; ++i) {
                int eiv = wsi[WS_ADJE + i];
                int e = eiv >> 1;
                float si = (eiv & 1) ? sc : -sc;
                for (int j = o0 + lane; j < o1; j += 64) {
                    int ejv = wsi[WS_ADJE + j];
                    atomicAdd(&L1[(size_t)e * EE + (ejv >> 1)], (ejv & 1) ? si : -si);
                }
            }
        }
    }
}

extern "C" void kernel_launch(void* const* d_in, const int* in_sizes, int n_in,
                              void* d_out, int out_size, void* d_ws, size_t ws_size,
                              hipStream_t stream) {
    const float* x_n  = (const float*)d_in[0];
    const int*   ei_n = (const int*)  d_in[1];
    const float* ew_n = (const float*)d_in[2];
    const float* x_e  = (const float*)d_in[3];
    const int*   ei_e = (const int*)  d_in[4];
    const float* ew_e = (const float*)d_in[5];
    const int*   ei   = (const int*)  d_in[6];
    const float* x_n0 = (const float*)d_in[9];
    const float* x_e0 = (const float*)d_in[10];
    const float* Wn0  = (const float*)d_in[11];
    const float* Wn1  = (const float*)d_in[12];
    const float* bn   = (const float*)d_in[13];
    const float* We0  = (const float*)d_in[14];
    const float* We1  = (const float*)d_in[15];
    const float* be   = (const float*)d_in[16];

    float* out = (float*)d_out;
    float* wsf = (float*)d_ws;
    int*   wsi = (int*)d_ws;

    k_prep <<<640, 256, 0, stream>>>(x_n, x_e, Wn0, Wn1, We0, We1, wsf);
    k_agg  <<<256, 256, 0, stream>>>(ei_n, ew_n, ei_e, ew_e, wsf);
    k_score<<<32, 256, 0, stream>>>(ei, bn, be, wsf);
    k_mid  <<<256, 1024, 0, stream>>>(ei, out, wsf, wsi);
    k_final<<<256, 1024, 0, stream>>>(x_n, x_e, x_n0, x_e0, ei, out, wsf, wsi);
}

// Round 5
// 446.973 us; speedup vs baseline: 1.1106x; 1.1106x over previous
//
#include <hip/hip_runtime.h>
#include <math.h>

// Problem constants
#define NN   2048
#define EE   8192
#define CNF  256
#define MN   16384
#define ME   65536
#define KK   1024

// Output layout (float element offsets)
#define OUT_XN   ((size_t)0)
#define OUT_L0   ((size_t)262144)
#define OUT_XE   ((size_t)1310720)
#define OUT_L1   ((size_t)3407872)
#define OUT_PM   ((size_t)70516736)
#define OUT_XN0  ((size_t)78905344)
#define OUT_XE0  ((size_t)79167488)

// Workspace layout (element offsets)
#define WS_T1N    0
#define WS_SLINN  2048
#define WS_T1E    4096
#define WS_SLINE  12288
#define WS_SCN    20480
#define WS_SCE    22528
#define WS_JOINT  30720   // dead gap 30720..32767 (2048 floats) — no ws growth
#define WS_AGGN   32768
#define WS_AGGE   34816
#define WS_LAM    43008
#define WS_IDXK   43520
#define WS_RANK   44544
#define WS_OFFS   47616
#define WS_ADJE   66176   // int[16384]
#define WS_KEEPE  82560   // int[8192]

#define DCAP  8
#define PWR_T 64          // 96->64: Rayleigh error (lam_i/lam_1)^128-weighted, ~1e-4 rel
#define RBAD  0xFFFFu

// native vector for nontemporal builtin (HIP float4 is a class -> rejected)
typedef float vf4 __attribute__((ext_vector_type(4)));

// =====================================================================
// Kernel A: row dots (wave per row) + zero the ws accumulators.
// =====================================================================
__global__ void k_prep(const float* __restrict__ xn, const float* __restrict__ xe,
                       const float* __restrict__ Wn0, const float* __restrict__ Wn1,
                       const float* __restrict__ We0, const float* __restrict__ We1,
                       float* __restrict__ wsf) {
    if (blockIdx.x == 0) {   // zero accumulators (AGGN, AGGE) + joint
        for (int i = threadIdx.x; i < 2048; i += 256) wsf[WS_AGGN + i] = 0.f;
        for (int i = threadIdx.x; i < 8192; i += 256) wsf[WS_AGGE + i] = 0.f;
        for (int i = threadIdx.x; i < 2048; i += 256) wsf[WS_JOINT + i] = 0.f;
    }
    int gw = (blockIdx.x * blockDim.x + threadIdx.x) >> 6;
    int lane = threadIdx.x & 63;
    int wstr = (gridDim.x * blockDim.x) >> 6;
    for (int row = gw; row < NN + EE; row += wstr) {
        const float *x, *W0, *W1; float *t1, *sl; int r;
        if (row < NN) { r = row;      x = xn + (size_t)r * CNF; W0 = Wn0; W1 = Wn1; t1 = wsf + WS_T1N; sl = wsf + WS_SLINN; }
        else          { r = row - NN; x = xe + (size_t)r * CNF; W0 = We0; W1 = We1; t1 = wsf + WS_T1E; sl = wsf + WS_SLINE; }
        float4 xv = ((const float4*)x)[lane];
        float4 w0 = ((const float4*)W0)[lane];
        float4 w1 = ((const float4*)W1)[lane];
        float d0 = xv.x*w0.x + xv.y*w0.y + xv.z*w0.z + xv.w*w0.w;
        float d1 = xv.x*w1.x + xv.y*w1.y + xv.z*w1.z + xv.w*w1.w;
        #pragma unroll
        for (int o = 32; o > 0; o >>= 1) { d0 += __shfl_down(d0, o, 64); d1 += __shfl_down(d1, o, 64); }
        if (lane == 0) { t1[r] = d1; sl[r] = d0 + d1; }
    }
}

// =====================================================================
// Kernel B: conv-edge scatter, grid-wide (single-CU version cost ~200us).
// =====================================================================
__global__ void k_agg(const int* __restrict__ ein, const float* __restrict__ ewn,
                      const int* __restrict__ eie, const float* __restrict__ ewe,
                      float* __restrict__ wsf) {
    int i = blockIdx.x * blockDim.x + threadIdx.x;
    if (i < MN) {
        int s = ein[i], d = ein[MN + i];
        atomicAdd(wsf + WS_AGGN + d, ewn[i] * wsf[WS_T1N + s]);
    }
    if (i < ME) {
        int s = eie[i], d = eie[ME + i];
        atomicAdd(wsf + WS_AGGE + d, ewe[i] * wsf[WS_T1E + s]);
    }
}

// =====================================================================
// Kernel B2: grid-wide sigmoid scores + joint node score (order-indep
// pure atomicAdd into pre-zeroed joint).
// =====================================================================
__global__ void k_score(const int* __restrict__ ei,
                        const float* __restrict__ bn, const float* __restrict__ be,
                        float* __restrict__ wsf) {
    int i = blockIdx.x * blockDim.x + threadIdx.x;
    if (i < NN) {
        float z = wsf[WS_SLINN + i] - wsf[WS_AGGN + i] + bn[0];
        float s = 1.0f / (1.0f + expf(-z));
        wsf[WS_SCN + i] = s;
        atomicAdd(wsf + WS_JOINT + i, s);
    }
    if (i < EE) {
        float z = wsf[WS_SLINE + i] - wsf[WS_AGGE + i] + be[0];
        float s = 1.0f / (1.0f + expf(-z));
        wsf[WS_SCE + i] = s;
        float v = 0.125f * s;
        atomicAdd(wsf + WS_JOINT + ei[i], v);        // src (+1 in |B|)
        atomicAdd(wsf + WS_JOINT + ei[EE + i], v);   // dst (+1 in |B|; s==d -> 2x, matches ref)
    }
}

// --------------------------------------------------- block reduce (16 waves)
__device__ __forceinline__ float block_reduce_sum(float val, float* red) {
    #pragma unroll
    for (int o = 32; o > 0; o >>= 1) val += __shfl_down(val, o, 64);
    int lane = threadIdx.x & 63, wid = threadIdx.x >> 6;
    if (lane == 0) red[wid] = val;
    __syncthreads();
    float r = 0.0f;
    if (threadIdx.x < 16) {
        r = red[threadIdx.x];
        #pragma unroll
        for (int o = 8; o > 0; o >>= 1) r += __shfl_down(r, o, 16);
        if (threadIdx.x == 0) red[0] = r;
    }
    __syncthreads();
    float out = red[0];
    __syncthreads();
    return out;
}

// --------------------------------------------------- block inclusive scan
// 1024 threads (16 waves): per-wave shfl scan + 16-partial combine. 2 barriers.
// Caller must barrier before t16 is reused.
__device__ __forceinline__ int block_incl_scan_1024(int v, int* t16) {
    int lane = threadIdx.x & 63, wid = threadIdx.x >> 6;
    int x = v;
    #pragma unroll
    for (int o = 1; o < 64; o <<= 1) {
        int t = __shfl_up(x, o, 64);
        if (lane >= o) x += t;
    }
    if (lane == 63) t16[wid] = x;
    __syncthreads();
    if (threadIdx.x < 16) {
        int w = t16[threadIdx.x];
        #pragma unroll
        for (int o = 1; o < 16; o <<= 1) {
            int t = __shfl_up(w, o, 16);
            if ((int)threadIdx.x >= o) w += t;
        }
        t16[threadIdx.x] = w;
    }
    __syncthreads();
    int base = wid ? t16[wid - 1] : 0;
    return base + x;
}

// =====================================================================
// Kernel C: block 0 = serial chain P5..P9, fully LDS-resident;
// blocks 1..255 zero L0+L1+PM (306 MB, nontemporal) meanwhile.
// R1 lesson: SINGLE-WAVE power iteration REGRESSED 4x — needs wave
// parallelism + DCAP register preload.
// R2: radix-select top-K + shfl scans: -21us. R3: P3/P4 offload: -18us
// (confirms chain-bound, zero stays hidden).
// R4 lesson: 4-wave/4-node P9 REGRESSED +63us (suspected aj[4][8]
// scratch spill + 1 wave/SIMD latency exposure). P9 stays 16-wave,
// 1 node/thread, DCAP preload — barrier bill (~0.5us ea) is cheaper
// than exposing the LDS-latency chain.
// R5 (this): isolate R4's (a): per-wave P5 histograms only. Joint
// scores cluster in [0.5,2) -> shared 0xBF top byte -> pass-5 was a
// ~2048-deep same-address LDS atomic chain; 16x private bins cut it.
// =====================================================================
__global__ __launch_bounds__(1024) void k_mid(
        const int* __restrict__ ei,
        float* __restrict__ out, float* __restrict__ wsf, int* __restrict__ wsi) {
    int tid = threadIdx.x;
    if (blockIdx.x != 0) {
        // ------------- zeroers: L1, PM, L0 (nontemporal: no reuse pre-k_final) -------------
        size_t w = (size_t)(blockIdx.x - 1) * 1024 + tid;
        size_t ws = (size_t)(gridDim.x - 1) * 1024;
        vf4 z = (vf4)(0.0f);
        vf4* l1 = (vf4*)(out + OUT_L1);
        for (size_t p = w; p < (size_t)EE * EE / 4; p += ws) __builtin_nontemporal_store(z, &l1[p]);
        vf4* pm = (vf4*)(out + OUT_PM);
        for (size_t p = w; p < (size_t)KK * EE / 4; p += ws) __builtin_nontemporal_store(z, &pm[p]);
        vf4* l0 = (vf4*)(out + OUT_L0);
        for (size_t p = w; p < (size_t)KK * KK / 4; p += ws) __builtin_nontemporal_store(z, &l0[p]);
        return;
    }
    // ---------------- block 0: serial chain, LDS-resident ----------------
    __shared__ unsigned long long s_u64[2048];       // 16 KB: per-wave bins / deg+scan+cur / power v
    __shared__ unsigned short s_rank[2048];          // 4 KB
    __shared__ unsigned short s_adjo[16384 + DCAP];  // 32 KB (+pad for reg-preload)
    __shared__ float s_red[16];
    __shared__ int s_t16[16];
    int* s_i = (int*)s_u64;                          // 4096 ints, phase-aliased

    // P5: top-K via exact radix select on 43-bit key (sortkey<<11)|(2047-i).
    // Thread owns the ADJACENT pair (2t, 2t+1) so kept flags stay in regs.
    // Per-wave 256-bin histograms (16x256 = all of s_i) kill hot-bin
    // serialization; boundary wave sums the 16 slices directly.
    unsigned long long k0, k1;
    {
        int i0 = 2 * tid, i1 = 2 * tid + 1;
        float f0 = wsf[WS_JOINT + i0], f1 = wsf[WS_JOINT + i1];
        unsigned u0 = __float_as_uint(f0), u1 = __float_as_uint(f1);
        unsigned sk0 = (u0 & 0x80000000u) ? ~u0 : (u0 | 0x80000000u);
        unsigned sk1 = (u1 & 0x80000000u) ? ~u1 : (u1 | 0x80000000u);
        k0 = (((unsigned long long)sk0) << 11) | (unsigned long long)(2047 - i0);
        k1 = (((unsigned long long)sk1) << 11) | (unsigned long long)(2047 - i1);
    }
    unsigned long long prefix = 0ULL;
    int rem = KK;
    int wb = (tid >> 6) << 8;                  // this wave's histogram base
    #pragma unroll
    for (int p = 5; p >= 0; --p) {
        __syncthreads();                       // protect s_i reuse across passes
        for (int i = tid; i < 4096; i += 1024) s_i[i] = 0;
        __syncthreads();
        int sh = p << 3;
        unsigned long long ph = prefix >> (sh + 8);
        if ((k0 >> (sh + 8)) == ph) atomicAdd(&s_i[wb | (int)((k0 >> sh) & 255)], 1);
        if ((k1 >> (sh + 8)) == ph) atomicAdd(&s_i[wb | (int)((k1 >> sh) & 255)], 1);
        __syncthreads();
        if (tid < 64) {                        // wave 0: sum 16 slices + boundary digit
            int b0 = 0, b1 = 0, b2 = 0, b3 = 0;
            #pragma unroll
            for (int w = 0; w < 16; ++w) {
                int base = (w << 8) | (tid << 2);
                b0 += s_i[base]; b1 += s_i[base + 1]; b2 += s_i[base + 2]; b3 += s_i[base + 3];
            }
            int sl = b0 + b1 + b2 + b3;
            int si = sl;
            #pragma unroll
            for (int o = 1; o < 64; o <<= 1) {
                int t = __shfl_down(si, o, 64);
                if (tid + o < 64) si += t;
            }
            int sup = si - sl;                 // count with digit-group > this lane
            int sg3 = sup;
            int sg2 = sg3 + b3;
            int sg1 = sg2 + b2;
            int sg0 = sg1 + b1;
            // wave-lockstep: all slice reads retire before these stores
            if (sg0 < rem && rem <= sg0 + b0) { s_i[256] = (tid << 2) | 0; s_i[257] = rem - sg0; }
            if (sg1 < rem && rem <= sg1 + b1) { s_i[256] = (tid << 2) | 1; s_i[257] = rem - sg1; }
            if (sg2 < rem && rem <= sg2 + b2) { s_i[256] = (tid << 2) | 2; s_i[257] = rem - sg2; }
            if (sg3 < rem && rem <= sg3 + b3) { s_i[256] = (tid << 2) | 3; s_i[257] = rem - sg3; }
        }
        __syncthreads();
        prefix |= ((unsigned long long)(unsigned)s_i[256]) << sh;
        rem = s_i[257];
    }
    // prefix == exact 1024th-largest key. kept <=> key >= prefix (all keys distinct).
    {
        int a0 = (k0 >= prefix) ? 1 : 0;
        int a1 = (k1 >= prefix) ? 1 : 0;
        int pr = a0 + a1;
        __syncthreads();                       // s_i[256..257] reads done before t16/s_i reuse
        int incl = block_incl_scan_1024(pr, s_t16);
        int excl = incl - pr;
        int i0 = 2 * tid, i1 = 2 * tid + 1;
        int r0 = excl, r1 = excl + a0;
        s_rank[i0] = a0 ? (unsigned short)r0 : (unsigned short)RBAD;
        s_rank[i1] = a1 ? (unsigned short)r1 : (unsigned short)RBAD;
        wsi[WS_RANK + i0] = a0 ? r0 : -1;      // for k_final
        wsi[WS_RANK + i1] = a1 ? r1 : -1;
        if (a0) wsi[WS_IDXK + r0] = i0;
        if (a1) wsi[WS_IDXK + r1] = i1;
    }
    __syncthreads();

    // P6: degrees (LDS s_i[0..1023]) + keep_e flags (seq global write)
    s_i[tid] = 0;
    __syncthreads();
    for (int e = tid; e < EE; e += 1024) {
        int s = ei[e], d = ei[EE + e];
        unsigned rs = s_rank[s], rd = s_rank[d];
        int kept = (rs != RBAD && rd != RBAD);
        wsi[WS_KEEPE + e] = kept;
        if (kept && s != d) {
            atomicAdd(&s_i[(int)rs], 1);
            atomicAdd(&s_i[(int)rd], 1);
        }
    }
    __syncthreads();

    // P7: CSR offsets via shfl block scan; cur in s_i[2048..3071]
    {
        int dg = s_i[tid];
        int incl = block_incl_scan_1024(dg, s_t16);
        int offs = incl - dg;
        s_i[2048 + tid] = offs;                // cur
        wsi[WS_OFFS + tid] = offs;             // for k_final + power
        if (tid == 1023) wsi[WS_OFFS + 1024] = incl;
    }
    __syncthreads();

    // P8: CSR fill: adjo -> LDS u16 (power), adje -> global (k_final only)
    for (int e = tid; e < EE; e += 1024) {
        int s = ei[e], d = ei[EE + e];
        unsigned rs = s_rank[s], rd = s_rank[d];
        if (rs != RBAD && rd != RBAD && s != d) {
            int p = atomicAdd(&s_i[2048 + (int)rs], 1);
            s_adjo[p] = (unsigned short)rd;
            wsi[WS_ADJE + p] = (e << 1);
            int q = atomicAdd(&s_i[2048 + (int)rd], 1);
            s_adjo[q] = (unsigned short)rs;
            wsi[WS_ADJE + q] = (e << 1) | 1;
        }
    }
    __syncthreads();

    // P9: power iteration for lambda_max — 16 waves, 1 node/thread, DCAP
    // register-preloaded adjacency (v aliases s_i[0..2047] as floats;
    // offs read from GLOBAL before v-init to avoid alias hazard)
    {
        int o0 = wsi[WS_OFFS + tid];
        int d  = wsi[WS_OFFS + tid + 1] - o0;
        __syncthreads();
        float* v0 = (float*)s_u64;
        float* v1 = v0 + 1024;
        unsigned h = (unsigned)tid * 2654435761u + 911u;
        h ^= h >> 15; h *= 2246822519u; h ^= h >> 13;
        v0[tid] = (float)(h & 0xFFFFu) * (1.0f / 65536.0f) - 0.5f;
        int aj[DCAP];
        #pragma unroll
        for (int j = 0; j < DCAP; ++j) aj[j] = (j < d) ? (int)s_adjo[o0 + j] : 0;
        __syncthreads();
        float* vc = v0; float* vn = v1;
        for (int iter = 0; iter < PWR_T; ++iter) {
            float acc = 0.0f;
            #pragma unroll
            for (int j = 0; j < DCAP; ++j) acc += (j < d) ? vc[aj[j]] : 0.0f;
            for (int i = o0 + DCAP; i < o0 + d; ++i) acc += vc[(int)s_adjo[i]];
            float y = (float)d * vc[tid] - acc;
            if ((iter & 7) == 7) {
                float n2 = block_reduce_sum(y * y, s_red);
                y *= (n2 > 0.0f) ? rsqrtf(n2) : 0.0f;
            }
            vn[tid] = y;
            __syncthreads();
            float* tmp = vc; vc = vn; vn = tmp;
        }
        float acc = 0.0f;
        #pragma unroll
        for (int j = 0; j < DCAP; ++j) acc += (j < d) ? vc[aj[j]] : 0.0f;
        for (int i = o0 + DCAP; i < o0 + d; ++i) acc += vc[(int)s_adjo[i]];
        float y = (float)d * vc[tid] - acc;
        float rq = block_reduce_sum(vc[tid] * y, s_red);
        if (tid == 0) wsf[WS_LAM] = rq;
    }
}

// =====================================================================
// Kernel D: all output writes that depend on the chain (2/lam folded).
// =====================================================================
__global__ __launch_bounds__(1024) void k_final(
        const float* __restrict__ xn, const float* __restrict__ xe,
        const float* __restrict__ xn0, const float* __restrict__ xe0,
        const int* __restrict__ ei,
        float* __restrict__ out, const float* __restrict__ wsf,
        const int* __restrict__ wsi) {
    float sc = 2.0f / wsf[WS_LAM];
    int gt = blockIdx.x * 1024 + threadIdx.x;
    int gstr = gridDim.x * 1024;

    // (a) kept-node feature gathers (rows fully overwritten, no pre-zero)
    for (int i = gt; i < KK * 64; i += gstr) {
        int r = i >> 6, c = i & 63;
        int src = wsi[WS_IDXK + r];
        float s = wsf[WS_SCN + src];
        float4 v = ((const float4*)(xn + (size_t)src * CNF))[c];
        v.x *= s; v.y *= s; v.z *= s; v.w *= s;
        ((float4*)(out + OUT_XN))[(size_t)r * 64 + c] = v;
        ((float4*)(out + OUT_XN0))[(size_t)r * 64 + c] = ((const float4*)(xn0 + (size_t)src * CNF))[c];
    }
    // (b) edge feature rows, written densely (kept: scaled; dropped: x*0)
    for (int i = gt; i < EE * 64; i += gstr) {
        int e = i >> 6, c = i & 63;
        float m = wsi[WS_KEEPE + e] ? 1.0f : 0.0f;
        float s = m * wsf[WS_SCE + e];
        float4 v = ((const float4*)(xe + (size_t)e * CNF))[c];
        v.x *= s; v.y *= s; v.z *= s; v.w *= s;
        ((float4*)(out + OUT_XE))[(size_t)e * 64 + c] = v;
        float4 v0 = ((const float4*)(xe0 + (size_t)e * CNF))[c];
        v0.x *= m; v0.y *= m; v0.z *= m; v0.w *= m;
        ((float4*)(out + OUT_XE0))[(size_t)e * 64 + c] = v0;
    }
    // (c) par_masked + L0 scatter (pre-zeroed in k_mid)
    {
        float* pm = out + OUT_PM;
        float* L0 = out + OUT_L0;
        for (int e = gt; e < EE; e += gstr) {
            int s = ei[e], d = ei[EE + e];
            int rs = wsi[WS_RANK + s], rd = wsi[WS_RANK + d];
            if (rs < 0 || rd < 0 || s == d) continue;
            pm[(size_t)rs * EE + e] = -1.0f;
            pm[(size_t)rd * EE + e] =  1.0f;
            atomicAdd(&L0[(size_t)rs * KK + rs],  sc);
            atomicAdd(&L0[(size_t)rd * KK + rd],  sc);
            atomicAdd(&L0[(size_t)rs * KK + rd], -sc);
            atomicAdd(&L0[(size_t)rd * KK + rs], -sc);
        }
    }
    // (d) L1 scatter: wave per node-row, lanes over inner pairs
    {
        float* L1 = out + OUT_L1;
        int gwv = gt >> 6, lane = gt & 63, wstr = gstr >> 6;
        for (int r = gwv; r < KK; r += wstr) {
            int o0 = wsi[WS_OFFS + r], o1 = wsi[WS_OFFS + r + 1];
            for (int i = o0; i < o1; ++i) {
                int eiv = wsi[WS_ADJE + i];
                int e = eiv >> 1;
                float si = (eiv & 1) ? sc : -sc;
                for (int j = o0 + lane; j < o1; j += 64) {
                    int ejv = wsi[WS_ADJE + j];
                    atomicAdd(&L1[(size_t)e * EE + (ejv >> 1)], (ejv & 1) ? si : -si);
                }
            }
        }
    }
}

extern "C" void kernel_launch(void* const* d_in, const int* in_sizes, int n_in,
                              void* d_out, int out_size, void* d_ws, size_t ws_size,
                              hipStream_t stream) {
    const float* x_n  = (const float*)d_in[0];
    const int*   ei_n = (const int*)  d_in[1];
    const float* ew_n = (const float*)d_in[2];
    const float* x_e  = (const float*)d_in[3];
    const int*   ei_e = (const int*)  d_in[4];
    const float* ew_e = (const float*)d_in[5];
    const int*   ei   = (const int*)  d_in[6];
    const float* x_n0 = (const float*)d_in[9];
    const float* x_e0 = (const float*)d_in[10];
    const float* Wn0  = (const float*)d_in[11];
    const float* Wn1  = (const float*)d_in[12];
    const float* bn   = (const float*)d_in[13];
    const float* We0  = (const float*)d_in[14];
    const float* We1  = (const float*)d_in[15];
    const float* be   = (const float*)d_in[16];

    float* out = (float*)d_out;
    float* wsf = (float*)d_ws;
    int*   wsi = (int*)d_ws;

    k_prep <<<640, 256, 0, stream>>>(x_n, x_e, Wn0, Wn1, We0, We1, wsf);
    k_agg  <<<256, 256, 0, stream>>>(ei_n, ew_n, ei_e, ew_e, wsf);
    k_score<<<32, 256, 0, stream>>>(ei, bn, be, wsf);
    k_mid  <<<256, 1024, 0, stream>>>(ei, out, wsf, wsi);
    k_final<<<256, 1024, 0, stream>>>(x_n, x_e, x_n0, x_e0, ei, out, wsf, wsi);
}

// Round 6
// 439.336 us; speedup vs baseline: 1.1299x; 1.0174x over previous
//
#include <hip/hip_runtime.h>
#include <math.h>

// Problem constants
#define NN   2048
#define EE   8192
#define CNF  256
#define MN   16384
#define ME   65536
#define KK   1024

// Output layout (float element offsets)
#define OUT_XN   ((size_t)0)
#define OUT_L0   ((size_t)262144)
#define OUT_XE   ((size_t)1310720)
#define OUT_L1   ((size_t)3407872)
#define OUT_PM   ((size_t)70516736)
#define OUT_XN0  ((size_t)78905344)
#define OUT_XE0  ((size_t)79167488)

// Workspace layout (element offsets)
#define WS_T1N    0
#define WS_SLINN  2048
#define WS_T1E    4096
#define WS_SLINE  12288
#define WS_SCN    20480
#define WS_SCE    22528
#define WS_JOINT  30720   // dead gap 30720..32767 (2048 floats) — no ws growth
#define WS_AGGN   32768
#define WS_AGGE   34816
#define WS_LAM    43008
#define WS_IDXK   43520
#define WS_RANK   44544
#define WS_OFFS   47616
#define WS_ADJE   66176   // int[16384]
#define WS_KEEPE  82560   // int[8192]

#define DCAP  8
#define PWR_T 64          // 96->64: Rayleigh error (lam_i/lam_1)^128-weighted, ~1e-4 rel
#define RBAD  0xFFFFu

// native vector for nontemporal builtin (HIP float4 is a class -> rejected)
typedef float vf4 __attribute__((ext_vector_type(4)));

// =====================================================================
// Kernel A: row dots (wave per row) + zero the ws accumulators.
// =====================================================================
__global__ void k_prep(const float* __restrict__ xn, const float* __restrict__ xe,
                       const float* __restrict__ Wn0, const float* __restrict__ Wn1,
                       const float* __restrict__ We0, const float* __restrict__ We1,
                       float* __restrict__ wsf) {
    if (blockIdx.x == 0) {   // zero accumulators (AGGN, AGGE) + joint
        for (int i = threadIdx.x; i < 2048; i += 256) wsf[WS_AGGN + i] = 0.f;
        for (int i = threadIdx.x; i < 8192; i += 256) wsf[WS_AGGE + i] = 0.f;
        for (int i = threadIdx.x; i < 2048; i += 256) wsf[WS_JOINT + i] = 0.f;
    }
    int gw = (blockIdx.x * blockDim.x + threadIdx.x) >> 6;
    int lane = threadIdx.x & 63;
    int wstr = (gridDim.x * blockDim.x) >> 6;
    for (int row = gw; row < NN + EE; row += wstr) {
        const float *x, *W0, *W1; float *t1, *sl; int r;
        if (row < NN) { r = row;      x = xn + (size_t)r * CNF; W0 = Wn0; W1 = Wn1; t1 = wsf + WS_T1N; sl = wsf + WS_SLINN; }
        else          { r = row - NN; x = xe + (size_t)r * CNF; W0 = We0; W1 = We1; t1 = wsf + WS_T1E; sl = wsf + WS_SLINE; }
        float4 xv = ((const float4*)x)[lane];
        float4 w0 = ((const float4*)W0)[lane];
        float4 w1 = ((const float4*)W1)[lane];
        float d0 = xv.x*w0.x + xv.y*w0.y + xv.z*w0.z + xv.w*w0.w;
        float d1 = xv.x*w1.x + xv.y*w1.y + xv.z*w1.z + xv.w*w1.w;
        #pragma unroll
        for (int o = 32; o > 0; o >>= 1) { d0 += __shfl_down(d0, o, 64); d1 += __shfl_down(d1, o, 64); }
        if (lane == 0) { t1[r] = d1; sl[r] = d0 + d1; }
    }
}

// =====================================================================
// Kernel B: conv-edge scatter, grid-wide (single-CU version cost ~200us).
// =====================================================================
__global__ void k_agg(const int* __restrict__ ein, const float* __restrict__ ewn,
                      const int* __restrict__ eie, const float* __restrict__ ewe,
                      float* __restrict__ wsf) {
    int i = blockIdx.x * blockDim.x + threadIdx.x;
    if (i < MN) {
        int s = ein[i], d = ein[MN + i];
        atomicAdd(wsf + WS_AGGN + d, ewn[i] * wsf[WS_T1N + s]);
    }
    if (i < ME) {
        int s = eie[i], d = eie[ME + i];
        atomicAdd(wsf + WS_AGGE + d, ewe[i] * wsf[WS_T1E + s]);
    }
}

// =====================================================================
// Kernel B2: grid-wide sigmoid scores + joint node score (order-indep
// pure atomicAdd into pre-zeroed joint).
// =====================================================================
__global__ void k_score(const int* __restrict__ ei,
                        const float* __restrict__ bn, const float* __restrict__ be,
                        float* __restrict__ wsf) {
    int i = blockIdx.x * blockDim.x + threadIdx.x;
    if (i < NN) {
        float z = wsf[WS_SLINN + i] - wsf[WS_AGGN + i] + bn[0];
        float s = 1.0f / (1.0f + expf(-z));
        wsf[WS_SCN + i] = s;
        atomicAdd(wsf + WS_JOINT + i, s);
    }
    if (i < EE) {
        float z = wsf[WS_SLINE + i] - wsf[WS_AGGE + i] + be[0];
        float s = 1.0f / (1.0f + expf(-z));
        wsf[WS_SCE + i] = s;
        float v = 0.125f * s;
        atomicAdd(wsf + WS_JOINT + ei[i], v);        // src (+1 in |B|)
        atomicAdd(wsf + WS_JOINT + ei[EE + i], v);   // dst (+1 in |B|; s==d -> 2x, matches ref)
    }
}

// --------------------------------------------------- block reduce (16 waves)
__device__ __forceinline__ float block_reduce_sum(float val, float* red) {
    #pragma unroll
    for (int o = 32; o > 0; o >>= 1) val += __shfl_down(val, o, 64);
    int lane = threadIdx.x & 63, wid = threadIdx.x >> 6;
    if (lane == 0) red[wid] = val;
    __syncthreads();
    float r = 0.0f;
    if (threadIdx.x < 16) {
        r = red[threadIdx.x];
        #pragma unroll
        for (int o = 8; o > 0; o >>= 1) r += __shfl_down(r, o, 16);
        if (threadIdx.x == 0) red[0] = r;
    }
    __syncthreads();
    float out = red[0];
    __syncthreads();
    return out;
}

// --------------------------------------------------- block inclusive scan
// 1024 threads (16 waves): per-wave shfl scan + 16-partial combine. 2 barriers.
// Caller must barrier before t16 is reused.
__device__ __forceinline__ int block_incl_scan_1024(int v, int* t16) {
    int lane = threadIdx.x & 63, wid = threadIdx.x >> 6;
    int x = v;
    #pragma unroll
    for (int o = 1; o < 64; o <<= 1) {
        int t = __shfl_up(x, o, 64);
        if (lane >= o) x += t;
    }
    if (lane == 63) t16[wid] = x;
    __syncthreads();
    if (threadIdx.x < 16) {
        int w = t16[threadIdx.x];
        #pragma unroll
        for (int o = 1; o < 16; o <<= 1) {
            int t = __shfl_up(w, o, 16);
            if ((int)threadIdx.x >= o) w += t;
        }
        t16[threadIdx.x] = w;
    }
    __syncthreads();
    int base = wid ? t16[wid - 1] : 0;
    return base + x;
}

// =====================================================================
// Kernel C: block 0 = serial chain P5..P9, fully LDS-resident;
// blocks 1..255 zero L0+L1+PM (306 MB, nontemporal) meanwhile.
// R1 lesson: SINGLE-WAVE power iteration REGRESSED 4x — needs wave
// parallelism + DCAP register preload.
// R2: radix-select top-K + shfl scans: -21us. R3: P3/P4 offload: -18us
// (chain-bound confirmed; zero stays hidden).
// R4 lesson: 4-wave/4-node P9 REGRESSED +63us (TLP loss / latency
// exposure). P9 stays 16-wave, 1 node/thread, DCAP preload.
// R5 lesson: per-wave P5 histograms REGRESSED +14us — same-address LDS
// atomicAdd is NOT a serialization disaster on CDNA4; single 256-bin
// histogram is the right shape. Serialization theory retired.
// R6 (this): P5 = 4 passes on the 32-bit float key (was 6 on 43-bit),
// exact index-asc tie-break via eq-scan; double-buffered bins so the
// next pass's zeroing overlaps wave-0's boundary scan (2 barriers/pass,
// was 4). Strictly less work + fewer barriers; identical kept set.
// =====================================================================
__global__ __launch_bounds__(1024) void k_mid(
        const int* __restrict__ ei,
        float* __restrict__ out, float* __restrict__ wsf, int* __restrict__ wsi) {
    int tid = threadIdx.x;
    if (blockIdx.x != 0) {
        // ------------- zeroers: L1, PM, L0 (nontemporal: no reuse pre-k_final) -------------
        size_t w = (size_t)(blockIdx.x - 1) * 1024 + tid;
        size_t ws = (size_t)(gridDim.x - 1) * 1024;
        vf4 z = (vf4)(0.0f);
        vf4* l1 = (vf4*)(out + OUT_L1);
        for (size_t p = w; p < (size_t)EE * EE / 4; p += ws) __builtin_nontemporal_store(z, &l1[p]);
        vf4* pm = (vf4*)(out + OUT_PM);
        for (size_t p = w; p < (size_t)KK * EE / 4; p += ws) __builtin_nontemporal_store(z, &pm[p]);
        vf4* l0 = (vf4*)(out + OUT_L0);
        for (size_t p = w; p < (size_t)KK * KK / 4; p += ws) __builtin_nontemporal_store(z, &l0[p]);
        return;
    }
    // ---------------- block 0: serial chain, LDS-resident ----------------
    __shared__ unsigned long long s_u64[2048];       // 16 KB: bins / deg+scan+cur / power v
    __shared__ unsigned short s_rank[2048];          // 4 KB
    __shared__ unsigned short s_adjo[16384 + DCAP];  // 32 KB (+pad for reg-preload)
    __shared__ float s_red[16];
    __shared__ int s_t16[16];
    int* s_i = (int*)s_u64;                          // 4096 ints, phase-aliased

    // P5: top-K exact select, 4 radix passes on 32-bit monotone key.
    // binA = s_i[0..255], binB = s_i[256..511] (double-buffered);
    // boundary digit/rem at s_i[512..513]. While wave 0 scans the
    // current bins, waves 1..4 zero the other buffer (disjoint LDS).
    unsigned sk0, sk1;
    {
        float f0 = wsf[WS_JOINT + 2 * tid], f1 = wsf[WS_JOINT + 2 * tid + 1];
        unsigned u0 = __float_as_uint(f0), u1 = __float_as_uint(f1);
        sk0 = (u0 & 0x80000000u) ? ~u0 : (u0 | 0x80000000u);
        sk1 = (u1 & 0x80000000u) ? ~u1 : (u1 | 0x80000000u);
    }
    if (tid < 256) s_i[tid] = 0;                   // zero binA
    __syncthreads();
    unsigned prefix = 0u;
    int rem = KK;
    #pragma unroll
    for (int p = 3; p >= 0; --p) {
        int sh = p << 3;
        int cur = ((3 - p) & 1) << 8;              // 0,256,0,256
        if (p == 3 || (sk0 >> (sh + 8)) == (prefix >> (sh + 8)))
            atomicAdd(&s_i[cur + (int)((sk0 >> sh) & 255u)], 1);
        if (p == 3 || (sk1 >> (sh + 8)) == (prefix >> (sh + 8)))
            atomicAdd(&s_i[cur + (int)((sk1 >> sh) & 255u)], 1);
        __syncthreads();
        if (tid < 64) {                            // wave 0: suffix scan + boundary digit
            int b0 = s_i[cur + 4 * tid + 0], b1 = s_i[cur + 4 * tid + 1];
            int b2 = s_i[cur + 4 * tid + 2], b3 = s_i[cur + 4 * tid + 3];
            int sl = b0 + b1 + b2 + b3;
            int si = sl;
            #pragma unroll
            for (int o = 1; o < 64; o <<= 1) {
                int t = __shfl_down(si, o, 64);
                if (tid + o < 64) si += t;
            }
            int sup = si - sl;                     // count with digit-group > this lane
            int sg3 = sup;
            int sg2 = sg3 + b3;
            int sg1 = sg2 + b2;
            int sg0 = sg1 + b1;
            if (sg0 < rem && rem <= sg0 + b0) { s_i[512] = (tid << 2) | 0; s_i[513] = rem - sg0; }
            if (sg1 < rem && rem <= sg1 + b1) { s_i[512] = (tid << 2) | 1; s_i[513] = rem - sg1; }
            if (sg2 < rem && rem <= sg2 + b2) { s_i[512] = (tid << 2) | 2; s_i[513] = rem - sg2; }
            if (sg3 < rem && rem <= sg3 + b3) { s_i[512] = (tid << 2) | 3; s_i[513] = rem - sg3; }
        } else if (tid < 320) {
            s_i[(cur ^ 256) + (tid - 64)] = 0;     // zero next buffer off the critical path
        }
        __syncthreads();
        prefix |= ((unsigned)s_i[512]) << sh;
        rem = s_i[513];
    }
    // prefix == pivot key (K-th largest, duplicates counted); rem = how many
    // pivot-equal keys to keep, lowest indices first (matches stable argsort).
    {
        int st0 = (sk0 > prefix) ? 1 : 0, eq0 = (sk0 == prefix) ? 1 : 0;
        int st1 = (sk1 > prefix) ? 1 : 0, eq1 = (sk1 == prefix) ? 1 : 0;
        int einc = block_incl_scan_1024(eq0 + eq1, s_t16);
        int eexc0 = einc - eq0 - eq1;
        int eexc1 = eexc0 + eq0;
        int a0 = st0 | (eq0 & ((eexc0 < rem) ? 1 : 0));
        int a1 = st1 | (eq1 & ((eexc1 < rem) ? 1 : 0));
        __syncthreads();                           // t16 reuse guard
        int incl = block_incl_scan_1024(a0 + a1, s_t16);
        int excl = incl - a0 - a1;
        int i0 = 2 * tid, i1 = 2 * tid + 1;
        int r0 = excl, r1 = excl + a0;
        s_rank[i0] = a0 ? (unsigned short)r0 : (unsigned short)RBAD;
        s_rank[i1] = a1 ? (unsigned short)r1 : (unsigned short)RBAD;
        wsi[WS_RANK + i0] = a0 ? r0 : -1;          // for k_final
        wsi[WS_RANK + i1] = a1 ? r1 : -1;
        if (a0) wsi[WS_IDXK + r0] = i0;
        if (a1) wsi[WS_IDXK + r1] = i1;
    }
    __syncthreads();

    // P6: degrees (LDS s_i[0..1023]) + keep_e flags (seq global write)
    s_i[tid] = 0;
    __syncthreads();
    for (int e = tid; e < EE; e += 1024) {
        int s = ei[e], d = ei[EE + e];
        unsigned rs = s_rank[s], rd = s_rank[d];
        int kept = (rs != RBAD && rd != RBAD);
        wsi[WS_KEEPE + e] = kept;
        if (kept && s != d) {
            atomicAdd(&s_i[(int)rs], 1);
            atomicAdd(&s_i[(int)rd], 1);
        }
    }
    __syncthreads();

    // P7: CSR offsets via shfl block scan; cur in s_i[2048..3071]
    {
        int dg = s_i[tid];
        int incl = block_incl_scan_1024(dg, s_t16);
        int offs = incl - dg;
        s_i[2048 + tid] = offs;                // cur
        wsi[WS_OFFS + tid] = offs;             // for k_final + power
        if (tid == 1023) wsi[WS_OFFS + 1024] = incl;
    }
    __syncthreads();

    // P8: CSR fill: adjo -> LDS u16 (power), adje -> global (k_final only)
    for (int e = tid; e < EE; e += 1024) {
        int s = ei[e], d = ei[EE + e];
        unsigned rs = s_rank[s], rd = s_rank[d];
        if (rs != RBAD && rd != RBAD && s != d) {
            int p = atomicAdd(&s_i[2048 + (int)rs], 1);
            s_adjo[p] = (unsigned short)rd;
            wsi[WS_ADJE + p] = (e << 1);
            int q = atomicAdd(&s_i[2048 + (int)rd], 1);
            s_adjo[q] = (unsigned short)rs;
            wsi[WS_ADJE + q] = (e << 1) | 1;
        }
    }
    __syncthreads();

    // P9: power iteration for lambda_max — 16 waves, 1 node/thread, DCAP
    // register-preloaded adjacency (v aliases s_i[0..2047] as floats;
    // offs read from GLOBAL before v-init to avoid alias hazard)
    {
        int o0 = wsi[WS_OFFS + tid];
        int d  = wsi[WS_OFFS + tid + 1] - o0;
        __syncthreads();
        float* v0 = (float*)s_u64;
        float* v1 = v0 + 1024;
        unsigned h = (unsigned)tid * 2654435761u + 911u;
        h ^= h >> 15; h *= 2246822519u; h ^= h >> 13;
        v0[tid] = (float)(h & 0xFFFFu) * (1.0f / 65536.0f) - 0.5f;
        int aj[DCAP];
        #pragma unroll
        for (int j = 0; j < DCAP; ++j) aj[j] = (j < d) ? (int)s_adjo[o0 + j] : 0;
        __syncthreads();
        float* vc = v0; float* vn = v1;
        for (int iter = 0; iter < PWR_T; ++iter) {
            float acc = 0.0f;
            #pragma unroll
            for (int j = 0; j < DCAP; ++j) acc += (j < d) ? vc[aj[j]] : 0.0f;
            for (int i = o0 + DCAP; i < o0 + d; ++i) acc += vc[(int)s_adjo[i]];
            float y = (float)d * vc[tid] - acc;
            if ((iter & 7) == 7) {
                float n2 = block_reduce_sum(y * y, s_red);
                y *= (n2 > 0.0f) ? rsqrtf(n2) : 0.0f;
            }
            vn[tid] = y;
            __syncthreads();
            float* tmp = vc; vc = vn; vn = tmp;
        }
        float acc = 0.0f;
        #pragma unroll
        for (int j = 0; j < DCAP; ++j) acc += (j < d) ? vc[aj[j]] : 0.0f;
        for (int i = o0 + DCAP; i < o0 + d; ++i) acc += vc[(int)s_adjo[i]];
        float y = (float)d * vc[tid] - acc;
        float rq = block_reduce_sum(vc[tid] * y, s_red);
        if (tid == 0) wsf[WS_LAM] = rq;
    }
}

// =====================================================================
// Kernel D: all output writes that depend on the chain (2/lam folded).
// =====================================================================
__global__ __launch_bounds__(1024) void k_final(
        const float* __restrict__ xn, const float* __restrict__ xe,
        const float* __restrict__ xn0, const float* __restrict__ xe0,
        const int* __restrict__ ei,
        float* __restrict__ out, const float* __restrict__ wsf,
        const int* __restrict__ wsi) {
    float sc = 2.0f / wsf[WS_LAM];
    int gt = blockIdx.x * 1024 + threadIdx.x;
    int gstr = gridDim.x * 1024;

    // (a) kept-node feature gathers (rows fully overwritten, no pre-zero)
    for (int i = gt; i < KK * 64; i += gstr) {
        int r = i >> 6, c = i & 63;
        int src = wsi[WS_IDXK + r];
        float s = wsf[WS_SCN + src];
        float4 v = ((const float4*)(xn + (size_t)src * CNF))[c];
        v.x *= s; v.y *= s; v.z *= s; v.w *= s;
        ((float4*)(out + OUT_XN))[(size_t)r * 64 + c] = v;
        ((float4*)(out + OUT_XN0))[(size_t)r * 64 + c] = ((const float4*)(xn0 + (size_t)src * CNF))[c];
    }
    // (b) edge feature rows, written densely (kept: scaled; dropped: x*0)
    for (int i = gt; i < EE * 64; i += gstr) {
        int e = i >> 6, c = i & 63;
        float m = wsi[WS_KEEPE + e] ? 1.0f : 0.0f;
        float s = m * wsf[WS_SCE + e];
        float4 v = ((const float4*)(xe + (size_t)e * CNF))[c];
        v.x *= s; v.y *= s; v.z *= s; v.w *= s;
        ((float4*)(out + OUT_XE))[(size_t)e * 64 + c] = v;
        float4 v0 = ((const float4*)(xe0 + (size_t)e * CNF))[c];
        v0.x *= m; v0.y *= m; v0.z *= m; v0.w *= m;
        ((float4*)(out + OUT_XE0))[(size_t)e * 64 + c] = v0;
    }
    // (c) par_masked + L0 scatter (pre-zeroed in k_mid)
    {
        float* pm = out + OUT_PM;
        float* L0 = out + OUT_L0;
        for (int e = gt; e < EE; e += gstr) {
            int s = ei[e], d = ei[EE + e];
            int rs = wsi[WS_RANK + s], rd = wsi[WS_RANK + d];
            if (rs < 0 || rd < 0 || s == d) continue;
            pm[(size_t)rs * EE + e] = -1.0f;
            pm[(size_t)rd * EE + e] =  1.0f;
            atomicAdd(&L0[(size_t)rs * KK + rs],  sc);
            atomicAdd(&L0[(size_t)rd * KK + rd],  sc);
            atomicAdd(&L0[(size_t)rs * KK + rd], -sc);
            atomicAdd(&L0[(size_t)rd * KK + rs], -sc);
        }
    }
    // (d) L1 scatter: wave per node-row, lanes over inner pairs
    {
        float* L1 = out + OUT_L1;
        int gwv = gt >> 6, lane = gt & 63, wstr = gstr >> 6;
        for (int r = gwv; r < KK; r += wstr) {
            int o0 = wsi[WS_OFFS + r], o1 = wsi[WS_OFFS + r + 1];
            for (int i = o0; i < o1; ++i) {
                int eiv = wsi[WS_ADJE + i];
                int e = eiv >> 1;
                float si = (eiv & 1) ? sc : -sc;
                for (int j = o0 + lane; j < o1; j += 64) {
                    int ejv = wsi[WS_ADJE + j];
                    atomicAdd(&L1[(size_t)e * EE + (ejv >> 1)], (ejv & 1) ? si : -si);
                }
            }
        }
    }
}

extern "C" void kernel_launch(void* const* d_in, const int* in_sizes, int n_in,
                              void* d_out, int out_size, void* d_ws, size_t ws_size,
                              hipStream_t stream) {
    const float* x_n  = (const float*)d_in[0];
    const int*   ei_n = (const int*)  d_in[1];
    const float* ew_n = (const float*)d_in[2];
    const float* x_e  = (const float*)d_in[3];
    const int*   ei_e = (const int*)  d_in[4];
    const float* ew_e = (const float*)d_in[5];
    const int*   ei   = (const int*)  d_in[6];
    const float* x_n0 = (const float*)d_in[9];
    const float* x_e0 = (const float*)d_in[10];
    const float* Wn0  = (const float*)d_in[11];
    const float* Wn1  = (const float*)d_in[12];
    const float* bn   = (const float*)d_in[13];
    const float* We0  = (const float*)d_in[14];
    const float* We1  = (const float*)d_in[15];
    const float* be   = (const float*)d_in[16];

    float* out = (float*)d_out;
    float* wsf = (float*)d_ws;
    int*   wsi = (int*)d_ws;

    k_prep <<<640, 256, 0, stream>>>(x_n, x_e, Wn0, Wn1, We0, We1, wsf);
    k_agg  <<<256, 256, 0, stream>>>(ei_n, ew_n, ei_e, ew_e, wsf);
    k_score<<<32, 256, 0, stream>>>(ei, bn, be, wsf);
    k_mid  <<<256, 1024, 0, stream>>>(ei, out, wsf, wsi);
    k_final<<<256, 1024, 0, stream>>>(x_n, x_e, x_n0, x_e0, ei, out, wsf, wsi);
}

// Round 7
// 432.103 us; speedup vs baseline: 1.1488x; 1.0167x over previous
//
#include <hip/hip_runtime.h>
#include <math.h>

// Problem constants
#define NN   2048
#define EE   8192
#define CNF  256
#define MN   16384
#define ME   65536
#define KK   1024

// Output layout (float element offsets)
#define OUT_XN   ((size_t)0)
#define OUT_L0   ((size_t)262144)
#define OUT_XE   ((size_t)1310720)
#define OUT_L1   ((size_t)3407872)
#define OUT_PM   ((size_t)70516736)
#define OUT_XN0  ((size_t)78905344)
#define OUT_XE0  ((size_t)79167488)

// Workspace layout (element offsets)
#define WS_T1N    0
#define WS_SLINN  2048
#define WS_T1E    4096
#define WS_SLINE  12288
#define WS_SCN    20480
#define WS_SCE    22528
#define WS_JOINT  30720   // dead gap 30720..32767 (2048 floats) — no ws growth
#define WS_AGGN   32768
#define WS_AGGE   34816
#define WS_LAM    43008
#define WS_IDXK   43520
#define WS_RANK   44544
#define WS_OFFS   47616
#define WS_ADJE   66176   // int[16384]
#define WS_KEEPE  82560   // int[8192]

#define DCAP  8
#define PWR_T 64          // 96->64: Rayleigh error (lam_i/lam_1)^128-weighted, ~1e-4 rel
#define RBAD  0xFFFFu

// native vector for nontemporal builtin (HIP float4 is a class -> rejected)
typedef float vf4 __attribute__((ext_vector_type(4)));

// =====================================================================
// Kernel A: row dots (wave per row) + zero the ws accumulators.
// =====================================================================
__global__ void k_prep(const float* __restrict__ xn, const float* __restrict__ xe,
                       const float* __restrict__ Wn0, const float* __restrict__ Wn1,
                       const float* __restrict__ We0, const float* __restrict__ We1,
                       float* __restrict__ wsf) {
    if (blockIdx.x == 0) {   // zero accumulators (AGGN, AGGE) + joint
        for (int i = threadIdx.x; i < 2048; i += 256) wsf[WS_AGGN + i] = 0.f;
        for (int i = threadIdx.x; i < 8192; i += 256) wsf[WS_AGGE + i] = 0.f;
        for (int i = threadIdx.x; i < 2048; i += 256) wsf[WS_JOINT + i] = 0.f;
    }
    int gw = (blockIdx.x * blockDim.x + threadIdx.x) >> 6;
    int lane = threadIdx.x & 63;
    int wstr = (gridDim.x * blockDim.x) >> 6;
    for (int row = gw; row < NN + EE; row += wstr) {
        const float *x, *W0, *W1; float *t1, *sl; int r;
        if (row < NN) { r = row;      x = xn + (size_t)r * CNF; W0 = Wn0; W1 = Wn1; t1 = wsf + WS_T1N; sl = wsf + WS_SLINN; }
        else          { r = row - NN; x = xe + (size_t)r * CNF; W0 = We0; W1 = We1; t1 = wsf + WS_T1E; sl = wsf + WS_SLINE; }
        float4 xv = ((const float4*)x)[lane];
        float4 w0 = ((const float4*)W0)[lane];
        float4 w1 = ((const float4*)W1)[lane];
        float d0 = xv.x*w0.x + xv.y*w0.y + xv.z*w0.z + xv.w*w0.w;
        float d1 = xv.x*w1.x + xv.y*w1.y + xv.z*w1.z + xv.w*w1.w;
        #pragma unroll
        for (int o = 32; o > 0; o >>= 1) { d0 += __shfl_down(d0, o, 64); d1 += __shfl_down(d1, o, 64); }
        if (lane == 0) { t1[r] = d1; sl[r] = d0 + d1; }
    }
}

// =====================================================================
// Kernel B: conv-edge scatter, grid-wide (single-CU version cost ~200us).
// =====================================================================
__global__ void k_agg(const int* __restrict__ ein, const float* __restrict__ ewn,
                      const int* __restrict__ eie, const float* __restrict__ ewe,
                      float* __restrict__ wsf) {
    int i = blockIdx.x * blockDim.x + threadIdx.x;
    if (i < MN) {
        int s = ein[i], d = ein[MN + i];
        atomicAdd(wsf + WS_AGGN + d, ewn[i] * wsf[WS_T1N + s]);
    }
    if (i < ME) {
        int s = eie[i], d = eie[ME + i];
        atomicAdd(wsf + WS_AGGE + d, ewe[i] * wsf[WS_T1E + s]);
    }
}

// =====================================================================
// Kernel B2: grid-wide sigmoid scores + joint node score (order-indep
// pure atomicAdd into pre-zeroed joint).
// =====================================================================
__global__ void k_score(const int* __restrict__ ei,
                        const float* __restrict__ bn, const float* __restrict__ be,
                        float* __restrict__ wsf) {
    int i = blockIdx.x * blockDim.x + threadIdx.x;
    if (i < NN) {
        float z = wsf[WS_SLINN + i] - wsf[WS_AGGN + i] + bn[0];
        float s = 1.0f / (1.0f + expf(-z));
        wsf[WS_SCN + i] = s;
        atomicAdd(wsf + WS_JOINT + i, s);
    }
    if (i < EE) {
        float z = wsf[WS_SLINE + i] - wsf[WS_AGGE + i] + be[0];
        float s = 1.0f / (1.0f + expf(-z));
        wsf[WS_SCE + i] = s;
        float v = 0.125f * s;
        atomicAdd(wsf + WS_JOINT + ei[i], v);        // src (+1 in |B|)
        atomicAdd(wsf + WS_JOINT + ei[EE + i], v);   // dst (+1 in |B|; s==d -> 2x, matches ref)
    }
}

// --------------------------------------------------- block reduce, 1 barrier
// Write 16 wave-partials, barrier, then ALL threads sum the 16 partials via
// broadcast LDS reads. SAFETY: caller must have a __syncthreads between
// consecutive calls (P9's main loop barrier provides it) so red[] is not
// rewritten while stragglers read.
__device__ __forceinline__ float block_reduce_sum_1b(float val, float* red) {
    #pragma unroll
    for (int o = 32; o > 0; o >>= 1) val += __shfl_down(val, o, 64);
    int lane = threadIdx.x & 63, wid = threadIdx.x >> 6;
    if (lane == 0) red[wid] = val;
    __syncthreads();
    float r = 0.0f;
    #pragma unroll
    for (int j = 0; j < 16; ++j) r += red[j];
    return r;
}

// --------------------------------------------------- block inclusive scan
// 1024 threads (16 waves): per-wave shfl scan + 16-partial combine. 2 barriers.
// Caller must barrier before t16 is reused.
__device__ __forceinline__ int block_incl_scan_1024(int v, int* t16) {
    int lane = threadIdx.x & 63, wid = threadIdx.x >> 6;
    int x = v;
    #pragma unroll
    for (int o = 1; o < 64; o <<= 1) {
        int t = __shfl_up(x, o, 64);
        if (lane >= o) x += t;
    }
    if (lane == 63) t16[wid] = x;
    __syncthreads();
    if (threadIdx.x < 16) {
        int w = t16[threadIdx.x];
        #pragma unroll
        for (int o = 1; o < 16; o <<= 1) {
            int t = __shfl_up(w, o, 16);
            if ((int)threadIdx.x >= o) w += t;
        }
        t16[threadIdx.x] = w;
    }
    __syncthreads();
    int base = wid ? t16[wid - 1] : 0;
    return base + x;
}

// =====================================================================
// Kernel C: block 0 = serial chain P5..P9, fully LDS-resident;
// blocks 1..255 zero L0+L1+PM+XE+XE0 (322 MB, nontemporal) meanwhile.
// R1: single-wave P9 regressed 4x (needs 16-wave TLP + DCAP preload).
// R2: radix-select + shfl scans -21us. R3: P3/P4 offload -18us.
// R4: 4-wave P9 regressed +63us. R5: per-wave P5 hists regressed +14us
// (same-address LDS atomics are fine on CDNA4). R6: 4-pass P5 + tie
// scan = wash (+6) -> P5 micro-variants exhausted; keep r3's 6-pass.
// R7 (this): (i) P9 reduces 3 barriers -> 1 (broadcast-read combine);
// (ii) zeroers also clear XE/XE0 (hidden under chain) so k_final
// writes only ~25% kept edge rows (-56 MB serial post-chain traffic).
// =====================================================================
__global__ __launch_bounds__(1024) void k_mid(
        const int* __restrict__ ei,
        float* __restrict__ out, float* __restrict__ wsf, int* __restrict__ wsi) {
    int tid = threadIdx.x;
    if (blockIdx.x != 0) {
        // ------- zeroers: L1, PM, L0, XE, XE0 (nontemporal; no reuse pre-k_final) -------
        size_t w = (size_t)(blockIdx.x - 1) * 1024 + tid;
        size_t ws = (size_t)(gridDim.x - 1) * 1024;
        vf4 z = (vf4)(0.0f);
        vf4* l1 = (vf4*)(out + OUT_L1);
        for (size_t p = w; p < (size_t)EE * EE / 4; p += ws) __builtin_nontemporal_store(z, &l1[p]);
        vf4* pm = (vf4*)(out + OUT_PM);
        for (size_t p = w; p < (size_t)KK * EE / 4; p += ws) __builtin_nontemporal_store(z, &pm[p]);
        vf4* l0 = (vf4*)(out + OUT_L0);
        for (size_t p = w; p < (size_t)KK * KK / 4; p += ws) __builtin_nontemporal_store(z, &l0[p]);
        vf4* xe_ = (vf4*)(out + OUT_XE);
        for (size_t p = w; p < (size_t)EE * CNF / 4; p += ws) __builtin_nontemporal_store(z, &xe_[p]);
        vf4* xe0_ = (vf4*)(out + OUT_XE0);
        for (size_t p = w; p < (size_t)EE * CNF / 4; p += ws) __builtin_nontemporal_store(z, &xe0_[p]);
        return;
    }
    // ---------------- block 0: serial chain, LDS-resident ----------------
    __shared__ unsigned long long s_u64[2048];       // 16 KB: bins / deg+scan+cur / power v
    __shared__ unsigned short s_rank[2048];          // 4 KB
    __shared__ unsigned short s_adjo[16384 + DCAP];  // 32 KB (+pad for reg-preload)
    __shared__ float s_red[16];
    __shared__ int s_t16[16];
    int* s_i = (int*)s_u64;                          // 4096 ints, phase-aliased

    // P5: top-K via exact radix select on 43-bit key (sortkey<<11)|(2047-i).
    // Thread owns the ADJACENT pair (2t, 2t+1) so kept flags stay in regs.
    // Keys straight from global joint (written by k_score; L2-hot, coalesced).
    unsigned long long k0, k1;
    {
        int i0 = 2 * tid, i1 = 2 * tid + 1;
        float f0 = wsf[WS_JOINT + i0], f1 = wsf[WS_JOINT + i1];
        unsigned u0 = __float_as_uint(f0), u1 = __float_as_uint(f1);
        unsigned sk0 = (u0 & 0x80000000u) ? ~u0 : (u0 | 0x80000000u);
        unsigned sk1 = (u1 & 0x80000000u) ? ~u1 : (u1 | 0x80000000u);
        k0 = (((unsigned long long)sk0) << 11) | (unsigned long long)(2047 - i0);
        k1 = (((unsigned long long)sk1) << 11) | (unsigned long long)(2047 - i1);
    }
    unsigned long long prefix = 0ULL;
    int rem = KK;
    #pragma unroll
    for (int p = 5; p >= 0; --p) {
        __syncthreads();                       // protect s_i reuse across passes
        if (tid < 256) s_i[tid] = 0;
        __syncthreads();
        int sh = p << 3;
        unsigned long long ph = prefix >> (sh + 8);
        if ((k0 >> (sh + 8)) == ph) atomicAdd(&s_i[(int)((k0 >> sh) & 255)], 1);
        if ((k1 >> (sh + 8)) == ph) atomicAdd(&s_i[(int)((k1 >> sh) & 255)], 1);
        __syncthreads();
        if (tid < 64) {                        // wave 0: boundary digit via suffix scan
            int b0 = s_i[4 * tid + 0], b1 = s_i[4 * tid + 1];
            int b2 = s_i[4 * tid + 2], b3 = s_i[4 * tid + 3];
            int sl = b0 + b1 + b2 + b3;
            int si = sl;
            #pragma unroll
            for (int o = 1; o < 64; o <<= 1) {
                int t = __shfl_down(si, o, 64);
                if (tid + o < 64) si += t;
            }
            int sup = si - sl;                 // count with digit-group > this lane
            int sg3 = sup;
            int sg2 = sg3 + b3;
            int sg1 = sg2 + b2;
            int sg0 = sg1 + b1;
            if (sg0 < rem && rem <= sg0 + b0) { s_i[256] = (tid << 2) | 0; s_i[257] = rem - sg0; }
            if (sg1 < rem && rem <= sg1 + b1) { s_i[256] = (tid << 2) | 1; s_i[257] = rem - sg1; }
            if (sg2 < rem && rem <= sg2 + b2) { s_i[256] = (tid << 2) | 2; s_i[257] = rem - sg2; }
            if (sg3 < rem && rem <= sg3 + b3) { s_i[256] = (tid << 2) | 3; s_i[257] = rem - sg3; }
        }
        __syncthreads();
        prefix |= ((unsigned long long)(unsigned)s_i[256]) << sh;
        rem = s_i[257];
    }
    // prefix == exact 1024th-largest key. kept <=> key >= prefix (all keys distinct).
    {
        int a0 = (k0 >= prefix) ? 1 : 0;
        int a1 = (k1 >= prefix) ? 1 : 0;
        int pr = a0 + a1;
        __syncthreads();                       // s_i[256..257] reads done before t16/s_i reuse
        int incl = block_incl_scan_1024(pr, s_t16);
        int excl = incl - pr;
        int i0 = 2 * tid, i1 = 2 * tid + 1;
        int r0 = excl, r1 = excl + a0;
        s_rank[i0] = a0 ? (unsigned short)r0 : (unsigned short)RBAD;
        s_rank[i1] = a1 ? (unsigned short)r1 : (unsigned short)RBAD;
        wsi[WS_RANK + i0] = a0 ? r0 : -1;      // for k_final
        wsi[WS_RANK + i1] = a1 ? r1 : -1;
        if (a0) wsi[WS_IDXK + r0] = i0;
        if (a1) wsi[WS_IDXK + r1] = i1;
    }
    __syncthreads();

    // P6: degrees (LDS s_i[0..1023]) + keep_e flags (seq global write)
    s_i[tid] = 0;
    __syncthreads();
    for (int e = tid; e < EE; e += 1024) {
        int s = ei[e], d = ei[EE + e];
        unsigned rs = s_rank[s], rd = s_rank[d];
        int kept = (rs != RBAD && rd != RBAD);
        wsi[WS_KEEPE + e] = kept;
        if (kept && s != d) {
            atomicAdd(&s_i[(int)rs], 1);
            atomicAdd(&s_i[(int)rd], 1);
        }
    }
    __syncthreads();

    // P7: CSR offsets via shfl block scan; cur in s_i[2048..3071]
    {
        int dg = s_i[tid];
        int incl = block_incl_scan_1024(dg, s_t16);
        int offs = incl - dg;
        s_i[2048 + tid] = offs;                // cur
        wsi[WS_OFFS + tid] = offs;             // for k_final + power
        if (tid == 1023) wsi[WS_OFFS + 1024] = incl;
    }
    __syncthreads();

    // P8: CSR fill: adjo -> LDS u16 (power), adje -> global (k_final only)
    for (int e = tid; e < EE; e += 1024) {
        int s = ei[e], d = ei[EE + e];
        unsigned rs = s_rank[s], rd = s_rank[d];
        if (rs != RBAD && rd != RBAD && s != d) {
            int p = atomicAdd(&s_i[2048 + (int)rs], 1);
            s_adjo[p] = (unsigned short)rd;
            wsi[WS_ADJE + p] = (e << 1);
            int q = atomicAdd(&s_i[2048 + (int)rd], 1);
            s_adjo[q] = (unsigned short)rs;
            wsi[WS_ADJE + q] = (e << 1) | 1;
        }
    }
    __syncthreads();

    // P9: power iteration for lambda_max — 16 waves, 1 node/thread, DCAP
    // register-preloaded adjacency (v aliases s_i[0..2047] as floats;
    // offs read from GLOBAL before v-init to avoid alias hazard).
    // block_reduce_sum_1b: 1 barrier/reduce; main loop barrier separates
    // consecutive calls (s_red reuse safety).
    {
        int o0 = wsi[WS_OFFS + tid];
        int d  = wsi[WS_OFFS + tid + 1] - o0;
        __syncthreads();
        float* v0 = (float*)s_u64;
        float* v1 = v0 + 1024;
        unsigned h = (unsigned)tid * 2654435761u + 911u;
        h ^= h >> 15; h *= 2246822519u; h ^= h >> 13;
        v0[tid] = (float)(h & 0xFFFFu) * (1.0f / 65536.0f) - 0.5f;
        int aj[DCAP];
        #pragma unroll
        for (int j = 0; j < DCAP; ++j) aj[j] = (j < d) ? (int)s_adjo[o0 + j] : 0;
        __syncthreads();
        float* vc = v0; float* vn = v1;
        for (int iter = 0; iter < PWR_T; ++iter) {
            float acc = 0.0f;
            #pragma unroll
            for (int j = 0; j < DCAP; ++j) acc += (j < d) ? vc[aj[j]] : 0.0f;
            for (int i = o0 + DCAP; i < o0 + d; ++i) acc += vc[(int)s_adjo[i]];
            float y = (float)d * vc[tid] - acc;
            if ((iter & 7) == 7) {
                float n2 = block_reduce_sum_1b(y * y, s_red);
                y *= (n2 > 0.0f) ? rsqrtf(n2) : 0.0f;
            }
            vn[tid] = y;
            __syncthreads();
            float* tmp = vc; vc = vn; vn = tmp;
        }
        float acc = 0.0f;
        #pragma unroll
        for (int j = 0; j < DCAP; ++j) acc += (j < d) ? vc[aj[j]] : 0.0f;
        for (int i = o0 + DCAP; i < o0 + d; ++i) acc += vc[(int)s_adjo[i]];
        float y = (float)d * vc[tid] - acc;
        float rq = block_reduce_sum_1b(vc[tid] * y, s_red);
        if (tid == 0) wsf[WS_LAM] = rq;
    }
}

// =====================================================================
// Kernel D: all output writes that depend on the chain (2/lam folded).
// (b) writes ONLY kept edge rows — dropped rows pre-zeroed by k_mid.
// =====================================================================
__global__ __launch_bounds__(1024) void k_final(
        const float* __restrict__ xn, const float* __restrict__ xe,
        const float* __restrict__ xn0, const float* __restrict__ xe0,
        const int* __restrict__ ei,
        float* __restrict__ out, const float* __restrict__ wsf,
        const int* __restrict__ wsi) {
    float sc = 2.0f / wsf[WS_LAM];
    int gt = blockIdx.x * 1024 + threadIdx.x;
    int gstr = gridDim.x * 1024;

    // (a) kept-node feature gathers (rows fully overwritten, no pre-zero)
    for (int i = gt; i < KK * 64; i += gstr) {
        int r = i >> 6, c = i & 63;
        int src = wsi[WS_IDXK + r];
        float s = wsf[WS_SCN + src];
        float4 v = ((const float4*)(xn + (size_t)src * CNF))[c];
        v.x *= s; v.y *= s; v.z *= s; v.w *= s;
        ((float4*)(out + OUT_XN))[(size_t)r * 64 + c] = v;
        ((float4*)(out + OUT_XN0))[(size_t)r * 64 + c] = ((const float4*)(xn0 + (size_t)src * CNF))[c];
    }
    // (b) edge feature rows, KEPT ONLY (dropped rows zeroed by k_mid zeroers);
    // wave-uniform skip: each wave (64 lanes) owns exactly one 256-float row.
    for (int i = gt; i < EE * 64; i += gstr) {
        int e = i >> 6;
        if (!wsi[WS_KEEPE + e]) continue;
        int c = i & 63;
        float s = wsf[WS_SCE + e];
        float4 v = ((const float4*)(xe + (size_t)e * CNF))[c];
        v.x *= s; v.y *= s; v.z *= s; v.w *= s;
        ((float4*)(out + OUT_XE))[(size_t)e * 64 + c] = v;
        ((float4*)(out + OUT_XE0))[(size_t)e * 64 + c] = ((const float4*)(xe0 + (size_t)e * CNF))[c];
    }
    // (c) par_masked + L0 scatter (pre-zeroed in k_mid)
    {
        float* pm = out + OUT_PM;
        float* L0 = out + OUT_L0;
        for (int e = gt; e < EE; e += gstr) {
            int s = ei[e], d = ei[EE + e];
            int rs = wsi[WS_RANK + s], rd = wsi[WS_RANK + d];
            if (rs < 0 || rd < 0 || s == d) continue;
            pm[(size_t)rs * EE + e] = -1.0f;
            pm[(size_t)rd * EE + e] =  1.0f;
            atomicAdd(&L0[(size_t)rs * KK + rs],  sc);
            atomicAdd(&L0[(size_t)rd * KK + rd],  sc);
            atomicAdd(&L0[(size_t)rs * KK + rd], -sc);
            atomicAdd(&L0[(size_t)rd * KK + rs], -sc);
        }
    }
    // (d) L1 scatter: wave per node-row, lanes over inner pairs
    {
        float* L1 = out + OUT_L1;
        int gwv = gt >> 6, lane = gt & 63, wstr = gstr >> 6;
        for (int r = gwv; r < KK; r += wstr) {
            int o0 = wsi[WS_OFFS + r], o1 = wsi[WS_OFFS + r + 1];
            for (int i = o0; i < o1; ++i) {
                int eiv = wsi[WS_ADJE + i];
                int e = eiv >> 1;
                float si = (eiv & 1) ? sc : -sc;
                for (int j = o0 + lane; j < o1; j += 64) {
                    int ejv = wsi[WS_ADJE + j];
                    atomicAdd(&L1[(size_t)e * EE + (ejv >> 1)], (ejv & 1) ? si : -si);
                }
            }
        }
    }
}

extern "C" void kernel_launch(void* const* d_in, const int* in_sizes, int n_in,
                              void* d_out, int out_size, void* d_ws, size_t ws_size,
                              hipStream_t stream) {
    const float* x_n  = (const float*)d_in[0];
    const int*   ei_n = (const int*)  d_in[1];
    const float* ew_n = (const float*)d_in[2];
    const float* x_e  = (const float*)d_in[3];
    const int*   ei_e = (const int*)  d_in[4];
    const float* ew_e = (const float*)d_in[5];
    const int*   ei   = (const int*)  d_in[6];
    const float* x_n0 = (const float*)d_in[9];
    const float* x_e0 = (const float*)d_in[10];
    const float* Wn0  = (const float*)d_in[11];
    const float* Wn1  = (const float*)d_in[12];
    const float* bn   = (const float*)d_in[13];
    const float* We0  = (const float*)d_in[14];
    const float* We1  = (const float*)d_in[15];
    const float* be   = (const float*)d_in[16];

    float* out = (float*)d_out;
    float* wsf = (float*)d_ws;
    int*   wsi = (int*)d_ws;

    k_prep <<<640, 256, 0, stream>>>(x_n, x_e, Wn0, Wn1, We0, We1, wsf);
    k_agg  <<<256, 256, 0, stream>>>(ei_n, ew_n, ei_e, ew_e, wsf);
    k_score<<<32, 256, 0, stream>>>(ei, bn, be, wsf);
    k_mid  <<<256, 1024, 0, stream>>>(ei, out, wsf, wsi);
    k_final<<<256, 1024, 0, stream>>>(x_n, x_e, x_n0, x_e0, ei, out, wsf, wsi);
}